// Round 6
// baseline (1511.863 us; speedup 1.0000x reference)
//
#include <hip/hip_runtime.h>

// Viterbi decode (CRF): B=128, T=4096, L=64.
// Outputs: score[B] (f32), path[B][T] (written as float labels).
constexpr int kB = 128;
constexpr int kT = 4096;
constexpr int kL = 64;
constexpr int kSeg = 64;     // number of backtrace segments
constexpr int kSegLen = 64;  // rows per segment (last segment has 63)
constexpr float kNeg = -10000.0f;

// ---------------- K1A forward: all-VALU broadcast via permlane+DPP ----------
// Lane i owns label i; delta lives in ONE register. Broadcast of all 64
// delta values to every lane is done with:
//   (a,b) = v_permlane32_swap(d,d)  -> {c0,c1,c0,c1}, {c2,c3,c2,c3}   (1 VALU op)
//   sw(a), sw(b) via ds_swizzle xor:16 -> row-swapped variants         (2 DS ops)
//   per base: 15 x v_add_f32_dpp row_ror:k + 1 plain add (fused DPP)
// Transitions are pre-gathered per-lane in the permuted order at init, so no
// per-step shuffling of tr. No LDS buffer, no lgkmcnt(0) drains.

// v_add_f32 with DPP row_ror applied to src0 (the rotating base).
#define ADD_ROR(dst, base, trv, K)                                              \
  asm("v_add_f32_dpp %0, %1, %2 row_ror:" #K " row_mask:0xf bank_mask:0xf"      \
      : "=v"(dst)                                                               \
      : "v"(base), "v"(trv))

__device__ __forceinline__ float reduce16(float base, const float (&tr)[16]) {
  float t0, t1, t2, t3, t4, t5, t6, t7, t8, t9, t10, t11, t12, t13, t14, t15;
  t0 = base + tr[0];
  ADD_ROR(t1, base, tr[1], 1);
  ADD_ROR(t2, base, tr[2], 2);
  ADD_ROR(t3, base, tr[3], 3);
  ADD_ROR(t4, base, tr[4], 4);
  ADD_ROR(t5, base, tr[5], 5);
  ADD_ROR(t6, base, tr[6], 6);
  ADD_ROR(t7, base, tr[7], 7);
  ADD_ROR(t8, base, tr[8], 8);
  ADD_ROR(t9, base, tr[9], 9);
  ADD_ROR(t10, base, tr[10], 10);
  ADD_ROR(t11, base, tr[11], 11);
  ADD_ROR(t12, base, tr[12], 12);
  ADD_ROR(t13, base, tr[13], 13);
  ADD_ROR(t14, base, tr[14], 14);
  ADD_ROR(t15, base, tr[15], 15);
  float m0 = fmaxf(fmaxf(t0, t1), fmaxf(t2, t3));
  float m1 = fmaxf(fmaxf(t4, t5), fmaxf(t6, t7));
  float m2 = fmaxf(fmaxf(t8, t9), fmaxf(t10, t11));
  float m3 = fmaxf(fmaxf(t12, t13), fmaxf(t14, t15));
  return fmaxf(fmaxf(m0, m1), fmaxf(m2, m3));
}

__device__ __forceinline__ float step_dpp(const float (&trb)[4][16], float d, float f) {
  float a = d, b = d;
  asm("v_permlane32_swap_b32 %0, %1" : "+v"(a), "+v"(b));
  // issue the two row-swaps early; latency hides under the a/b reductions
  int sai = __builtin_amdgcn_ds_swizzle(__float_as_int(a), 0x401F);  // xor lane^16
  int sbi = __builtin_amdgcn_ds_swizzle(__float_as_int(b), 0x401F);
  float acc0 = reduce16(a, trb[0]);
  float acc1 = reduce16(b, trb[1]);
  float acc2 = reduce16(__int_as_float(sai), trb[2]);
  float acc3 = reduce16(__int_as_float(sbi), trb[3]);
  return fmaxf(fmaxf(acc0, acc1), fmaxf(acc2, acc3)) + f;
}

__global__ __launch_bounds__(64, 1) void fwd_delta(const float* __restrict__ feats,
                                                   const float* __restrict__ trans,
                                                   float* __restrict__ delta) {
  const int i = threadIdx.x;
  const int b = blockIdx.x;
  const size_t kBL = (size_t)kB * kL;

  // --- probe permlane32_swap output order (uniform, once) ---
  int pa = i, pb = i;
  asm("v_permlane32_swap_b32 %0, %1" : "+v"(pa), "+v"(pb));
  // pa is either lo-dup {0..31,0..31} (firstlane 0) or hi-dup (firstlane 32).
  const int aHi = (__builtin_amdgcn_readfirstlane(pa) == 32) ? 1 : 0;

  // --- gather transitions in the permuted order ---
  // base0 = a-output: chunk 2*aHi + (r&1); base1 = b-output: 2*(1-aHi) + (r&1)
  // base2 = sw16(a): 2*aHi + 1-(r&1);     base3 = sw16(b): 2*(1-aHi) + 1-(r&1)
  // row_ror:k delivers base[(p-k)&15] to position p.
  const int r1 = (i >> 4) & 1;
  const int p = i & 15;
  int ch0 = 2 * aHi + r1;
  int ch1 = 2 * (1 - aHi) + r1;
  int ch2 = 2 * aHi + (1 - r1);
  int ch3 = 2 * (1 - aHi) + (1 - r1);
  float trb[4][16];
#pragma unroll
  for (int k = 0; k < 16; ++k) {
    const int pk = (p - k) & 15;
    trb[0][k] = trans[i * kL + 16 * ch0 + pk];
    trb[1][k] = trans[i * kL + 16 * ch1 + pk];
    trb[2][k] = trans[i * kL + 16 * ch2 + pk];
    trb[3][k] = trans[i * kL + 16 * ch3 + pk];
  }

  float d = (i == 62) ? 0.0f : kNeg;
  float* drow = delta + (size_t)b * kL + i;  // layout [T][B][L]
  *drow = d;
  drow += kBL;
  const float* fp = feats + (size_t)b * kT * kL + i;
  // 4-deep feat prefetch ring; no clamping in the main loop.
  float f0 = fp[64 * 1], f1 = fp[64 * 2], f2 = fp[64 * 3], f3 = fp[64 * 4];
  const float* pf = fp + 64 * 5;
  for (int it = 0; it < 1022; ++it) {
    d = step_dpp(trb, d, f0);
    *drow = d; drow += kBL; f0 = pf[0];
    d = step_dpp(trb, d, f1);
    *drow = d; drow += kBL; f1 = pf[64];
    d = step_dpp(trb, d, f2);
    *drow = d; drow += kBL; f2 = pf[128];
    d = step_dpp(trb, d, f3);
    *drow = d; drow += kBL; f3 = pf[192];
    pf += 256;
  }
  // pf now points at row t=4093. Steps remaining: 4089..4095 (7 steps).
  float g0 = pf[0], g1 = pf[64], g2 = pf[128];
  d = step_dpp(trb, d, f0); *drow = d; drow += kBL;
  d = step_dpp(trb, d, f1); *drow = d; drow += kBL;
  d = step_dpp(trb, d, f2); *drow = d; drow += kBL;
  d = step_dpp(trb, d, f3); *drow = d; drow += kBL;
  d = step_dpp(trb, d, g0); *drow = d; drow += kBL;
  d = step_dpp(trb, d, g1); *drow = d; drow += kBL;
  d = step_dpp(trb, d, g2); *drow = d;
}

// ---------------- K1B: forward with argmax (plan B fallback) ----------------
__device__ __forceinline__ void step_b(const float (&tr)[kL], float2* dl2, int i,
                                       float fcur, unsigned char*& prow, float& dcur) {
  asm volatile("s_waitcnt lgkmcnt(0)" ::: "memory");
  float bA = -INFINITY, bBv = -INFINITY;
  int iA = 0, iB = 32;
#pragma unroll
  for (int p = 0; p < 16; ++p) {
    float2 q = dl2[p];
    float c0 = tr[2 * p] + q.x;
    bool g0 = c0 > bA; bA = g0 ? c0 : bA; iA = g0 ? 2 * p : iA;
    float c1 = tr[2 * p + 1] + q.y;
    bool g1 = c1 > bA; bA = g1 ? c1 : bA; iA = g1 ? 2 * p + 1 : iA;
  }
#pragma unroll
  for (int p = 16; p < 32; ++p) {
    float2 q = dl2[p];
    float c0 = tr[2 * p] + q.x;
    bool g0 = c0 > bBv; bBv = g0 ? c0 : bBv; iB = g0 ? 2 * p : iB;
    float c1 = tr[2 * p + 1] + q.y;
    bool g1 = c1 > bBv; bBv = g1 ? c1 : bBv; iB = g1 ? 2 * p + 1 : iB;
  }
  bool gm = bBv > bA;  // strict: tie keeps lower-j half
  float nd = (gm ? bBv : bA) + fcur;
  *prow = (unsigned char)(gm ? iB : iA);
  prow += (size_t)kB * kL;
  asm volatile("s_waitcnt lgkmcnt(0)" ::: "memory");
  reinterpret_cast<float*>(dl2)[i] = nd;
  dcur = nd;
}

__global__ __launch_bounds__(64) void fwd_psi(const float* __restrict__ feats,
                                              const float* __restrict__ trans,
                                              unsigned char* __restrict__ psi,
                                              float* __restrict__ dfin) {
  const int i = threadIdx.x;
  const int b = blockIdx.x;
  float tr[kL];
#pragma unroll
  for (int k = 0; k < kL; k += 4) {
    float4 v = *reinterpret_cast<const float4*>(trans + i * kL + k);
    tr[k] = v.x; tr[k + 1] = v.y; tr[k + 2] = v.z; tr[k + 3] = v.w;
  }
  __shared__ float2 dl2[kL / 2];
  const float d0 = (i == 62) ? 0.0f : kNeg;
  reinterpret_cast<float*>(dl2)[i] = d0;
  unsigned char* prow = psi + (size_t)b * kL + i;
  const float* fb = feats + (size_t)b * kT * kL + i;
  float dcur = d0;
  float f0 = fb[(size_t)kL * 1], f1 = fb[(size_t)kL * 2];
  float f2 = fb[(size_t)kL * 3], f3 = fb[(size_t)kL * 4];
  int t = 1;
  for (int it = 0; it < 1023; ++it, t += 4) {
    step_b(tr, dl2, i, f0, prow, dcur);
    f0 = fb[(size_t)kL * (t + 4 < kT ? t + 4 : kT - 1)];
    step_b(tr, dl2, i, f1, prow, dcur);
    f1 = fb[(size_t)kL * (t + 5 < kT ? t + 5 : kT - 1)];
    step_b(tr, dl2, i, f2, prow, dcur);
    f2 = fb[(size_t)kL * (t + 6 < kT ? t + 6 : kT - 1)];
    step_b(tr, dl2, i, f3, prow, dcur);
    f3 = fb[(size_t)kL * (t + 7 < kT ? t + 7 : kT - 1)];
  }
  step_b(tr, dl2, i, f0, prow, dcur);
  step_b(tr, dl2, i, f1, prow, dcur);
  step_b(tr, dl2, i, f2, prow, dcur);
  dfin[(size_t)b * kL + i] = dcur;
}

// ---------------- K2: recompute backpointers from stored delta (plan A) ------
// row r = t*128 + b; delta layout [T][B][L] makes row base = delta + r*64.
__global__ __launch_bounds__(256) void psi_from_delta(const float* __restrict__ delta,
                                                      const float* __restrict__ trans,
                                                      unsigned char* __restrict__ psi) {
  const int lane = threadIdx.x & 63;
  const int w = __builtin_amdgcn_readfirstlane(blockIdx.x * 4 + (threadIdx.x >> 6));
  float tr[kL];
#pragma unroll
  for (int k = 0; k < kL; k += 4) {
    float4 v = *reinterpret_cast<const float4*>(trans + lane * kL + k);
    tr[k] = v.x; tr[k + 1] = v.y; tr[k + 2] = v.z; tr[k + 3] = v.w;
  }
  const int r0 = w * 8;  // 8 rows per wave; grid sized exactly
  for (int rr = 0; rr < 8; ++rr) {
    const int r = r0 + rr;
    const float4* row4 = reinterpret_cast<const float4*>(delta + (size_t)r * kL);
    float bA = -INFINITY, bBv = -INFINITY;
    int iA = 0, iB = 32;
#pragma unroll
    for (int q = 0; q < 8; ++q) {
      float4 dv = row4[q];
      float c; bool g;
      c = tr[4 * q + 0] + dv.x; g = c > bA; bA = g ? c : bA; iA = g ? 4 * q + 0 : iA;
      c = tr[4 * q + 1] + dv.y; g = c > bA; bA = g ? c : bA; iA = g ? 4 * q + 1 : iA;
      c = tr[4 * q + 2] + dv.z; g = c > bA; bA = g ? c : bA; iA = g ? 4 * q + 2 : iA;
      c = tr[4 * q + 3] + dv.w; g = c > bA; bA = g ? c : bA; iA = g ? 4 * q + 3 : iA;
    }
#pragma unroll
    for (int q = 8; q < 16; ++q) {
      float4 dv = row4[q];
      float c; bool g;
      c = tr[4 * q + 0] + dv.x; g = c > bBv; bBv = g ? c : bBv; iB = g ? 4 * q + 0 : iB;
      c = tr[4 * q + 1] + dv.y; g = c > bBv; bBv = g ? c : bBv; iB = g ? 4 * q + 1 : iB;
      c = tr[4 * q + 2] + dv.z; g = c > bBv; bBv = g ? c : bBv; iB = g ? 4 * q + 2 : iB;
      c = tr[4 * q + 3] + dv.w; g = c > bBv; bBv = g ? c : bBv; iB = g ? 4 * q + 3 : iB;
    }
    bool gm = bBv > bA;  // tie -> lower half (first occurrence)
    psi[(size_t)r * kL + lane] = (unsigned char)(gm ? iB : iA);
  }
}

// ---------------- K3: segment composition (in-place psi -> M) ----------------
__global__ __launch_bounds__(256) void seg_compose(unsigned char* psiM,
                                                   unsigned char* __restrict__ C) {
  const int lane = threadIdx.x & 63;
  const int w = blockIdx.x * 4 + (threadIdx.x >> 6);
  const int s = w >> 7;
  const int b = w & 127;
  const int tstart = s * kSegLen;
  const int tend = (tstart + kSegLen < kT) ? tstart + kSegLen : kT - 1;  // last seg: 4095
  const size_t stride = (size_t)kB * kL;
  size_t off = ((size_t)(tend - 1) * kB + b) * kL + lane;
  int m = lane;
  int v = psiM[off];
  for (int t = tend - 1; t > tstart; --t) {
    int vn = psiM[off - stride];          // prefetch next row
    m = __shfl(v, m, 64);                 // m = psi_row[m]
    psiM[off] = (unsigned char)m;         // M[t][b][e] = path[t] | hyp e
    v = vn;
    off -= stride;
  }
  m = __shfl(v, m, 64);
  psiM[off] = (unsigned char)m;
  C[((size_t)s * kB + b) * kL + lane] = (unsigned char)m;  // composed map
}

// ---------------- K4: score, last label, boundary-label scan ----------------
__global__ __launch_bounds__(64) void score_scan(const float* __restrict__ dfin,
                                                 const unsigned char* __restrict__ C,
                                                 int* __restrict__ E,
                                                 float* __restrict__ out) {
  const int b = blockIdx.x;
  const int i = threadIdx.x;
  float d = dfin[(size_t)b * kL + i];
  float m = d;
#pragma unroll
  for (int off = 32; off; off >>= 1) m = fmaxf(m, __shfl_xor(m, off, 64));
  unsigned long long msk = __ballot(d == m);
  int ll = __ffsll(msk) - 1;  // first (lowest) argmax lane
  if (i == 0) {
    out[b] = m;
    out[kB + (size_t)b * kT + (kT - 1)] = (float)ll;
    int lbl = ll;
    for (int s = kSeg - 1; s >= 0; --s) {
      E[s * kB + b] = lbl;                              // label at t_end(s)
      lbl = C[((size_t)s * kB + b) * kL + lbl];         // -> label at t_start(s)
    }
  }
}

// ---------------- K5: parallel path gather ----------------
__global__ __launch_bounds__(256) void path_fill(const unsigned char* __restrict__ M,
                                                 const int* __restrict__ E,
                                                 float* __restrict__ out) {
  const int n = blockIdx.x * 256 + threadIdx.x;  // n = b*4096 + t
  const int b = n >> 12;
  const int t = n & (kT - 1);
  if (t == kT - 1) return;  // written by score_scan
  const int e = E[(t >> 6) * kB + b];
  const unsigned char lab = M[((size_t)t * kB + b) * kL + e];
  out[kB + (size_t)b * kT + t] = (float)lab;
}

extern "C" void kernel_launch(void* const* d_in, const int* in_sizes, int n_in,
                              void* d_out, int out_size, void* d_ws, size_t ws_size,
                              hipStream_t stream) {
  const float* feats = (const float*)d_in[0];
  const float* trans = (const float*)d_in[1];
  float* out = (float*)d_out;
  char* ws = (char*)d_ws;

  const size_t deltaB = (size_t)kT * kB * kL * 4;   // 134,217,728
  const size_t psiB   = (size_t)kT * kB * kL;       //  33,554,432
  const size_t CBy    = (size_t)kSeg * kB * kL;     //     524,288
  const size_t EBy    = (size_t)kSeg * kB * 4;      //      32,768

  if (ws_size >= deltaB + psiB + CBy + EBy) {
    // Plan A: value-only forward + fully-parallel backpointer recompute.
    float* delta = (float*)ws;
    unsigned char* psi = (unsigned char*)(ws + deltaB);
    unsigned char* C = (unsigned char*)(ws + deltaB + psiB);
    int* E = (int*)(ws + deltaB + psiB + CBy);
    hipLaunchKernelGGL(fwd_delta, dim3(kB), dim3(64), 0, stream, feats, trans, delta);
    hipLaunchKernelGGL(psi_from_delta, dim3(16380), dim3(256), 0, stream, delta, trans, psi);
    hipLaunchKernelGGL(seg_compose, dim3(2048), dim3(256), 0, stream, psi, C);
    hipLaunchKernelGGL(score_scan, dim3(kB), dim3(64), 0, stream,
                       delta + (size_t)(kT - 1) * kB * kL, C, E, out);
    hipLaunchKernelGGL(path_fill, dim3(2048), dim3(256), 0, stream, psi, E, out);
  } else {
    // Plan B: argmax in forward (psi only, ~34 MB workspace).
    unsigned char* psi = (unsigned char*)ws;
    unsigned char* C = (unsigned char*)(ws + psiB);
    int* E = (int*)(ws + psiB + CBy);
    float* dfin = (float*)(ws + psiB + CBy + EBy);
    hipLaunchKernelGGL(fwd_psi, dim3(kB), dim3(64), 0, stream, feats, trans, psi, dfin);
    hipLaunchKernelGGL(seg_compose, dim3(2048), dim3(256), 0, stream, psi, C);
    hipLaunchKernelGGL(score_scan, dim3(kB), dim3(64), 0, stream, dfin, C, E, out);
    hipLaunchKernelGGL(path_fill, dim3(2048), dim3(256), 0, stream, psi, E, out);
  }
}

// Round 7
// 1358.376 us; speedup vs baseline: 1.1130x; 1.1130x over previous
//
#include <hip/hip_runtime.h>

// Viterbi decode (CRF): B=128, T=4096, L=64.
// Outputs: score[B] (f32), path[B][T] (written as float labels).
constexpr int kB = 128;
constexpr int kT = 4096;
constexpr int kL = 64;
constexpr int kSeg = 64;     // number of backtrace segments
constexpr int kSegLen = 64;  // rows per segment (last segment has 63)
constexpr float kNeg = -10000.0f;

typedef float f32x2 __attribute__((ext_vector_type(2)));
typedef float f32x4 __attribute__((ext_vector_type(4)));

// ---------------- K1A forward step: single-buffer LDS broadcast --------------
// One wave per batch; lane i owns output label i. delta published via ONE
// ds_write_b32 then read back as 16 uniform-address ds_read_b128 broadcasts.
// sched_barrier(0) after the read batch FORCES all 16 reads in flight before
// any compute (compiler otherwise sinks them into uses and re-pays LDS
// latency 2-3x per step — R5 measured 670cyc/step, VGPR only 72).
// Adds paired as v_pk_add_f32; max tree as v_pk_max_f32 (bitwise-exact:
// same IEEE adds, max is order-invariant).
__device__ __forceinline__ float step_lds(const f32x2 (&tr2)[kL / 2], float* dl,
                                          const f32x4* dl4, int i, float d, float f) {
  asm volatile("" ::: "memory");
  dl[i] = d;                       // publish delta(t-1); in-order DS pipe
  asm volatile("" ::: "memory");
  f32x4 v[16];
#pragma unroll
  for (int q = 0; q < 16; ++q) v[q] = dl4[q];  // 16x ds_read_b128
  __builtin_amdgcn_sched_barrier(0);           // keep ALL reads above compute
  f32x2 mm[16];
#pragma unroll
  for (int q = 0; q < 16; ++q) {
    f32x2 p = tr2[2 * q] + v[q].lo;      // v_pk_add_f32
    f32x2 r = tr2[2 * q + 1] + v[q].hi;
    mm[q] = __builtin_elementwise_max(p, r);  // v_pk_max_f32
  }
#pragma unroll
  for (int s = 8; s; s >>= 1)
    for (int q = 0; q < s; ++q) mm[q] = __builtin_elementwise_max(mm[q], mm[q + s]);
  return fmaxf(mm[0].x, mm[0].y) + f;
}

__global__ __launch_bounds__(64, 1) void fwd_delta(const float* __restrict__ feats,
                                                   const float* __restrict__ trans,
                                                   float* __restrict__ delta) {
  const int i = threadIdx.x;
  const int b = blockIdx.x;
  const size_t kBL = (size_t)kB * kL;
  f32x2 tr2[kL / 2];
#pragma unroll
  for (int k = 0; k < kL; k += 4) {
    float4 v = *reinterpret_cast<const float4*>(trans + i * kL + k);
    tr2[k / 2].x = v.x; tr2[k / 2].y = v.y;
    tr2[k / 2 + 1].x = v.z; tr2[k / 2 + 1].y = v.w;
  }
  __shared__ float dl[kL];
  const f32x4* dl4 = reinterpret_cast<const f32x4*>(dl);
  float d = (i == 62) ? 0.0f : kNeg;
  float* drow = delta + (size_t)b * kL + i;  // layout [T][B][L]
  *drow = d;
  drow += kBL;
  const float* fp = feats + (size_t)b * kT * kL + i;
  // 4-deep feat prefetch ring; no clamping in the main loop.
  float f0 = fp[64 * 1], f1 = fp[64 * 2], f2 = fp[64 * 3], f3 = fp[64 * 4];
  const float* pf = fp + 64 * 5;
  for (int it = 0; it < 1022; ++it) {
    d = step_lds(tr2, dl, dl4, i, d, f0);
    *drow = d; drow += kBL; f0 = pf[0];
    d = step_lds(tr2, dl, dl4, i, d, f1);
    *drow = d; drow += kBL; f1 = pf[64];
    d = step_lds(tr2, dl, dl4, i, d, f2);
    *drow = d; drow += kBL; f2 = pf[128];
    d = step_lds(tr2, dl, dl4, i, d, f3);
    *drow = d; drow += kBL; f3 = pf[192];
    pf += 256;
  }
  // pf now points at row t=4093. Steps remaining: 4089..4095 (7 steps).
  float g0 = pf[0], g1 = pf[64], g2 = pf[128];
  d = step_lds(tr2, dl, dl4, i, d, f0); *drow = d; drow += kBL;
  d = step_lds(tr2, dl, dl4, i, d, f1); *drow = d; drow += kBL;
  d = step_lds(tr2, dl, dl4, i, d, f2); *drow = d; drow += kBL;
  d = step_lds(tr2, dl, dl4, i, d, f3); *drow = d; drow += kBL;
  d = step_lds(tr2, dl, dl4, i, d, g0); *drow = d; drow += kBL;
  d = step_lds(tr2, dl, dl4, i, d, g1); *drow = d; drow += kBL;
  d = step_lds(tr2, dl, dl4, i, d, g2); *drow = d;
}

// ---------------- K1B: forward with argmax (plan B fallback) ----------------
__device__ __forceinline__ void step_b(const float (&tr)[kL], float2* dl2, int i,
                                       float fcur, unsigned char*& prow, float& dcur) {
  asm volatile("s_waitcnt lgkmcnt(0)" ::: "memory");
  float bA = -INFINITY, bBv = -INFINITY;
  int iA = 0, iB = 32;
#pragma unroll
  for (int p = 0; p < 16; ++p) {
    float2 q = dl2[p];
    float c0 = tr[2 * p] + q.x;
    bool g0 = c0 > bA; bA = g0 ? c0 : bA; iA = g0 ? 2 * p : iA;
    float c1 = tr[2 * p + 1] + q.y;
    bool g1 = c1 > bA; bA = g1 ? c1 : bA; iA = g1 ? 2 * p + 1 : iA;
  }
#pragma unroll
  for (int p = 16; p < 32; ++p) {
    float2 q = dl2[p];
    float c0 = tr[2 * p] + q.x;
    bool g0 = c0 > bBv; bBv = g0 ? c0 : bBv; iB = g0 ? 2 * p : iB;
    float c1 = tr[2 * p + 1] + q.y;
    bool g1 = c1 > bBv; bBv = g1 ? c1 : bBv; iB = g1 ? 2 * p + 1 : iB;
  }
  bool gm = bBv > bA;  // strict: tie keeps lower-j half
  float nd = (gm ? bBv : bA) + fcur;
  *prow = (unsigned char)(gm ? iB : iA);
  prow += (size_t)kB * kL;
  asm volatile("s_waitcnt lgkmcnt(0)" ::: "memory");
  reinterpret_cast<float*>(dl2)[i] = nd;
  dcur = nd;
}

__global__ __launch_bounds__(64) void fwd_psi(const float* __restrict__ feats,
                                              const float* __restrict__ trans,
                                              unsigned char* __restrict__ psi,
                                              float* __restrict__ dfin) {
  const int i = threadIdx.x;
  const int b = blockIdx.x;
  float tr[kL];
#pragma unroll
  for (int k = 0; k < kL; k += 4) {
    float4 v = *reinterpret_cast<const float4*>(trans + i * kL + k);
    tr[k] = v.x; tr[k + 1] = v.y; tr[k + 2] = v.z; tr[k + 3] = v.w;
  }
  __shared__ float2 dl2[kL / 2];
  const float d0 = (i == 62) ? 0.0f : kNeg;
  reinterpret_cast<float*>(dl2)[i] = d0;
  unsigned char* prow = psi + (size_t)b * kL + i;
  const float* fb = feats + (size_t)b * kT * kL + i;
  float dcur = d0;
  float f0 = fb[(size_t)kL * 1], f1 = fb[(size_t)kL * 2];
  float f2 = fb[(size_t)kL * 3], f3 = fb[(size_t)kL * 4];
  int t = 1;
  for (int it = 0; it < 1023; ++it, t += 4) {
    step_b(tr, dl2, i, f0, prow, dcur);
    f0 = fb[(size_t)kL * (t + 4 < kT ? t + 4 : kT - 1)];
    step_b(tr, dl2, i, f1, prow, dcur);
    f1 = fb[(size_t)kL * (t + 5 < kT ? t + 5 : kT - 1)];
    step_b(tr, dl2, i, f2, prow, dcur);
    f2 = fb[(size_t)kL * (t + 6 < kT ? t + 6 : kT - 1)];
    step_b(tr, dl2, i, f3, prow, dcur);
    f3 = fb[(size_t)kL * (t + 7 < kT ? t + 7 : kT - 1)];
  }
  step_b(tr, dl2, i, f0, prow, dcur);
  step_b(tr, dl2, i, f1, prow, dcur);
  step_b(tr, dl2, i, f2, prow, dcur);
  dfin[(size_t)b * kL + i] = dcur;
}

// ---------------- K2: recompute backpointers from stored delta (plan A) ------
// row r = t*128 + b; delta layout [T][B][L] makes row base = delta + r*64.
__global__ __launch_bounds__(256) void psi_from_delta(const float* __restrict__ delta,
                                                      const float* __restrict__ trans,
                                                      unsigned char* __restrict__ psi) {
  const int lane = threadIdx.x & 63;
  const int w = __builtin_amdgcn_readfirstlane(blockIdx.x * 4 + (threadIdx.x >> 6));
  float tr[kL];
#pragma unroll
  for (int k = 0; k < kL; k += 4) {
    float4 v = *reinterpret_cast<const float4*>(trans + lane * kL + k);
    tr[k] = v.x; tr[k + 1] = v.y; tr[k + 2] = v.z; tr[k + 3] = v.w;
  }
  const int r0 = w * 8;  // 8 rows per wave; grid sized exactly
  for (int rr = 0; rr < 8; ++rr) {
    const int r = r0 + rr;
    const float4* row4 = reinterpret_cast<const float4*>(delta + (size_t)r * kL);
    float bA = -INFINITY, bBv = -INFINITY;
    int iA = 0, iB = 32;
#pragma unroll
    for (int q = 0; q < 8; ++q) {
      float4 dv = row4[q];
      float c; bool g;
      c = tr[4 * q + 0] + dv.x; g = c > bA; bA = g ? c : bA; iA = g ? 4 * q + 0 : iA;
      c = tr[4 * q + 1] + dv.y; g = c > bA; bA = g ? c : bA; iA = g ? 4 * q + 1 : iA;
      c = tr[4 * q + 2] + dv.z; g = c > bA; bA = g ? c : bA; iA = g ? 4 * q + 2 : iA;
      c = tr[4 * q + 3] + dv.w; g = c > bA; bA = g ? c : bA; iA = g ? 4 * q + 3 : iA;
    }
#pragma unroll
    for (int q = 8; q < 16; ++q) {
      float4 dv = row4[q];
      float c; bool g;
      c = tr[4 * q + 0] + dv.x; g = c > bBv; bBv = g ? c : bBv; iB = g ? 4 * q + 0 : iB;
      c = tr[4 * q + 1] + dv.y; g = c > bBv; bBv = g ? c : bBv; iB = g ? 4 * q + 1 : iB;
      c = tr[4 * q + 2] + dv.z; g = c > bBv; bBv = g ? c : bBv; iB = g ? 4 * q + 2 : iB;
      c = tr[4 * q + 3] + dv.w; g = c > bBv; bBv = g ? c : bBv; iB = g ? 4 * q + 3 : iB;
    }
    bool gm = bBv > bA;  // tie -> lower half (first occurrence)
    psi[(size_t)r * kL + lane] = (unsigned char)(gm ? iB : iA);
  }
}

// ---------------- K3: segment composition (in-place psi -> M) ----------------
__global__ __launch_bounds__(256) void seg_compose(unsigned char* psiM,
                                                   unsigned char* __restrict__ C) {
  const int lane = threadIdx.x & 63;
  const int w = blockIdx.x * 4 + (threadIdx.x >> 6);
  const int s = w >> 7;
  const int b = w & 127;
  const int tstart = s * kSegLen;
  const int tend = (tstart + kSegLen < kT) ? tstart + kSegLen : kT - 1;  // last seg: 4095
  const size_t stride = (size_t)kB * kL;
  size_t off = ((size_t)(tend - 1) * kB + b) * kL + lane;
  int m = lane;
  int v = psiM[off];
  for (int t = tend - 1; t > tstart; --t) {
    int vn = psiM[off - stride];          // prefetch next row
    m = __shfl(v, m, 64);                 // m = psi_row[m]
    psiM[off] = (unsigned char)m;         // M[t][b][e] = path[t] | hyp e
    v = vn;
    off -= stride;
  }
  m = __shfl(v, m, 64);
  psiM[off] = (unsigned char)m;
  C[((size_t)s * kB + b) * kL + lane] = (unsigned char)m;  // composed map
}

// ---------------- K4: score, last label, boundary-label scan ----------------
__global__ __launch_bounds__(64) void score_scan(const float* __restrict__ dfin,
                                                 const unsigned char* __restrict__ C,
                                                 int* __restrict__ E,
                                                 float* __restrict__ out) {
  const int b = blockIdx.x;
  const int i = threadIdx.x;
  float d = dfin[(size_t)b * kL + i];
  float m = d;
#pragma unroll
  for (int off = 32; off; off >>= 1) m = fmaxf(m, __shfl_xor(m, off, 64));
  unsigned long long msk = __ballot(d == m);
  int ll = __ffsll(msk) - 1;  // first (lowest) argmax lane
  if (i == 0) {
    out[b] = m;
    out[kB + (size_t)b * kT + (kT - 1)] = (float)ll;
    int lbl = ll;
    for (int s = kSeg - 1; s >= 0; --s) {
      E[s * kB + b] = lbl;                              // label at t_end(s)
      lbl = C[((size_t)s * kB + b) * kL + lbl];         // -> label at t_start(s)
    }
  }
}

// ---------------- K5: parallel path gather ----------------
__global__ __launch_bounds__(256) void path_fill(const unsigned char* __restrict__ M,
                                                 const int* __restrict__ E,
                                                 float* __restrict__ out) {
  const int n = blockIdx.x * 256 + threadIdx.x;  // n = b*4096 + t
  const int b = n >> 12;
  const int t = n & (kT - 1);
  if (t == kT - 1) return;  // written by score_scan
  const int e = E[(t >> 6) * kB + b];
  const unsigned char lab = M[((size_t)t * kB + b) * kL + e];
  out[kB + (size_t)b * kT + t] = (float)lab;
}

extern "C" void kernel_launch(void* const* d_in, const int* in_sizes, int n_in,
                              void* d_out, int out_size, void* d_ws, size_t ws_size,
                              hipStream_t stream) {
  const float* feats = (const float*)d_in[0];
  const float* trans = (const float*)d_in[1];
  float* out = (float*)d_out;
  char* ws = (char*)d_ws;

  const size_t deltaB = (size_t)kT * kB * kL * 4;   // 134,217,728
  const size_t psiB   = (size_t)kT * kB * kL;       //  33,554,432
  const size_t CBy    = (size_t)kSeg * kB * kL;     //     524,288
  const size_t EBy    = (size_t)kSeg * kB * 4;      //      32,768

  if (ws_size >= deltaB + psiB + CBy + EBy) {
    // Plan A: value-only forward + fully-parallel backpointer recompute.
    float* delta = (float*)ws;
    unsigned char* psi = (unsigned char*)(ws + deltaB);
    unsigned char* C = (unsigned char*)(ws + deltaB + psiB);
    int* E = (int*)(ws + deltaB + psiB + CBy);
    hipLaunchKernelGGL(fwd_delta, dim3(kB), dim3(64), 0, stream, feats, trans, delta);
    hipLaunchKernelGGL(psi_from_delta, dim3(16380), dim3(256), 0, stream, delta, trans, psi);
    hipLaunchKernelGGL(seg_compose, dim3(2048), dim3(256), 0, stream, psi, C);
    hipLaunchKernelGGL(score_scan, dim3(kB), dim3(64), 0, stream,
                       delta + (size_t)(kT - 1) * kB * kL, C, E, out);
    hipLaunchKernelGGL(path_fill, dim3(2048), dim3(256), 0, stream, psi, E, out);
  } else {
    // Plan B: argmax in forward (psi only, ~34 MB workspace).
    unsigned char* psi = (unsigned char*)ws;
    unsigned char* C = (unsigned char*)(ws + psiB);
    int* E = (int*)(ws + psiB + CBy);
    float* dfin = (float*)(ws + psiB + CBy + EBy);
    hipLaunchKernelGGL(fwd_psi, dim3(kB), dim3(64), 0, stream, feats, trans, psi, dfin);
    hipLaunchKernelGGL(seg_compose, dim3(2048), dim3(256), 0, stream, psi, C);
    hipLaunchKernelGGL(score_scan, dim3(kB), dim3(64), 0, stream, dfin, C, E, out);
    hipLaunchKernelGGL(path_fill, dim3(2048), dim3(256), 0, stream, psi, E, out);
  }
}